// Round 13
// baseline (135.895 us; speedup 1.0000x reference)
//
#include <hip/hip_runtime.h>

#define IMG_H 512
#define IMG_W 512
#define N_IMG 24                          // B*C
#define NPIX (N_IMG * IMG_H * IMG_W)      // 6291456
#define TH 8                              // center rows per block
#define LR (TH + 4)                       // 12 staged rows
#define BLOCK 256
#define NBLOCKS (N_IMG * IMG_H / TH)      // 1536

__device__ __forceinline__ int reflect_row(int x) {   // PAD=2 reflect
    int a = x < 0 ? -x : x;
    int b = 2 * IMG_H - 2 - a;
    return a < b ? a : b;
}

__global__ void census_init(unsigned int* __restrict__ ws) {
    ws[0] = 0u;
    ws[1] = 0u;
}

// 5 census combos of one neighbor-row r against one center row's values
// (ct = {pred,gt} center pair). cnt is wave-uniform.
#define JBLOCK(ct, SKIPR)                                                     \
    {                                                                         \
        cnt += __popcll(__ballot(v0.x < ct.x) ^ __ballot(v0.y < ct.y));       \
        cnt += __popcll(__ballot(v1.x < ct.x) ^ __ballot(v1.y < ct.y));       \
        if (r != (SKIPR))                                                     \
            cnt += __popcll(__ballot(v2.x < ct.x) ^ __ballot(v2.y < ct.y));   \
        cnt += __popcll(__ballot(v3.x < ct.x) ^ __ballot(v3.y < ct.y));       \
        cnt += __popcll(__ballot(v4.x < ct.x) ^ __ballot(v4.y < ct.y));       \
    }

__global__ __launch_bounds__(BLOCK) void census_main(
    const float* __restrict__ pred, const float* __restrict__ gt,
    float* __restrict__ out, unsigned int* __restrict__ ws)
{
    __shared__ float2 ls[LR][IMG_W];      // interleaved {pred, gt}, 48 KB
    __shared__ int wave_sums[BLOCK / 64];

    const int tid = threadIdx.x;
    const int b   = blockIdx.x;
    const int img = b >> 6;               // 64 row-groups per image
    const int hb  = (b & 63) * TH;        // first center row of tile

    const float* __restrict__ pimg = pred + (size_t)img * IMG_H * IMG_W;
    const float* __restrict__ gimg = gt   + (size_t)img * IMG_H * IMG_W;

    // ---- stage 12 rows x 512 cols, both inputs interleaved ----
    #pragma unroll
    for (int k = 0; k < 6; ++k) {
        const int idx = tid + k * BLOCK;   // 0..1535
        const int row = idx >> 7;          // 0..11
        const int c4  = (idx & 127) << 2;  // 0..508
        const int gy  = reflect_row(hb - 2 + row);
        const float4 p4 = *(const float4*)(pimg + gy * IMG_W + c4);
        const float4 g4 = *(const float4*)(gimg + gy * IMG_W + c4);
        ls[row][c4 + 0] = make_float2(p4.x, g4.x);
        ls[row][c4 + 1] = make_float2(p4.y, g4.y);
        ls[row][c4 + 2] = make_float2(p4.z, g4.z);
        ls[row][c4 + 3] = make_float2(p4.w, g4.w);
    }
    __syncthreads();

    // ---- wave-ballot census, TIGHT ROLLED loops ----
    const int lane = tid & 63;
    const int wave = tid >> 6;
    int cnt = 0;                          // wave-uniform

    #pragma unroll 1
    for (int k = 0; k < 4; ++k) {
        const int u     = wave * 4 + k;   // 0..15
        const int rbase = (u & 1) * 4;    // row-group base
        const int cc    = (u >> 1) * 64 + lane;   // center col

        // reflect-clamped shifted cols, all NAMED scalars (no arrays)
        const int cx0 = abs(cc - 2);                       // dx=-2
        const int cx1 = abs(cc - 1);                       // dx=-1
        const int cx2 = cc;                                // dx= 0
        const int t3  = cc + 1;
        const int cx3 = min(t3, 1022 - t3);                // dx=+1
        const int t4  = cc + 2;
        const int cx4 = min(t4, 1022 - t4);                // dx=+2

        // center {pred,gt} pairs for the 4 center rows of this unit
        const float2 ct0 = ls[rbase + 2][cc];
        const float2 ct1 = ls[rbase + 3][cc];
        const float2 ct2 = ls[rbase + 4][cc];
        const float2 ct3 = ls[rbase + 5][cc];

        #pragma unroll 1
        for (int r = 0; r < 8; ++r) {     // staged rows rbase..rbase+7
            const float2* rowp = &ls[rbase + r][0];
            const float2 v0 = rowp[cx0];  // one ds_read_b64 each
            const float2 v1 = rowp[cx1];
            const float2 v2 = rowp[cx2];
            const float2 v3 = rowp[cx3];
            const float2 v4 = rowp[cx4];

            // center row j valid iff r in [j, j+4]; skip dx=0 at r==j+2
            if (r <= 4)           JBLOCK(ct0, 2)
            if (r >= 1 && r <= 5) JBLOCK(ct1, 3)
            if (r >= 2 && r <= 6) JBLOCK(ct2, 4)
            if (r >= 3)           JBLOCK(ct3, 5)
        }
    }

    // ---- block reduction: cnt is wave-uniform ----
    if (lane == 0) wave_sums[wave] = cnt;
    __syncthreads();

    if (tid == 0) {
        int total = wave_sums[0] + wave_sums[1] + wave_sums[2] + wave_sums[3];
        atomicAdd(&ws[0], (unsigned int)total);
        __threadfence();
        unsigned int r = atomicAdd(&ws[1], 1u);
        if (r == (unsigned int)(NBLOCKS - 1)) {
            unsigned int tot = atomicAdd(&ws[0], 0u);
            out[0] = (float)((double)tot / (double)NPIX);
        }
    }
}

extern "C" void kernel_launch(void* const* d_in, const int* in_sizes, int n_in,
                              void* d_out, int out_size, void* d_ws, size_t ws_size,
                              hipStream_t stream) {
    const float* pred = (const float*)d_in[0];
    const float* gt   = (const float*)d_in[1];
    float* out        = (float*)d_out;
    unsigned int* ws  = (unsigned int*)d_ws;

    census_init<<<1, 1, 0, stream>>>(ws);
    census_main<<<NBLOCKS, BLOCK, 0, stream>>>(pred, gt, out, ws);
}